// Round 9
// baseline (379.495 us; speedup 1.0000x reference)
//
#include <hip/hip_runtime.h>
#include <hip/hip_cooperative_groups.h>
#include <stdint.h>

namespace cg = cooperative_groups;

typedef unsigned int u32;
typedef unsigned short u16;
typedef short short8 __attribute__((ext_vector_type(8)));
typedef float f32x16 __attribute__((ext_vector_type(16)));

#define BN 8192
#define NPB 128           // partial tiles per batch (64 rows each)

__device__ __forceinline__ u32 f2b_u(float f){
  u32 x = __float_as_uint(f);
  return (x + 0x7fffu + ((x >> 16) & 1u)) >> 16;   // RNE f32->bf16
}
__device__ __forceinline__ float gelu_exact(float v){
  return 0.5f * v * (1.0f + erff(v * 0.70710678118654752440f));
}

// ===========================================================================
// FUSED cooperative kernel: P1 gram -> P2 reduceA -> P3 combine -> P4 out
// grid = 512 blocks (b = bid>>7, blk = bid&127), 256 threads.
// ===========================================================================
union SMem {
  struct { u16 xT[64][72]; float mred[256][16]; } g;               // 25.6 KB
  struct { float Gt[65*68]; float Tl[64*68]; float St[64*68]; } c; // 52.5 KB
};

__global__ __launch_bounds__(256, 2) void k_fused(
    const float* __restrict__ x,
    const float* __restrict__ Wq, const float* __restrict__ bq,
    const float* __restrict__ Wk, const float* __restrict__ bk,
    const float* __restrict__ Wv, const float* __restrict__ bv,
    const float* __restrict__ Ww, const float* __restrict__ bw,
    float* __restrict__ part, float* __restrict__ part2,
    float* __restrict__ Mt, float* __restrict__ out)
{
  cg::grid_group grid = cg::this_grid();
  __shared__ SMem sm;

  int bid = blockIdx.x;
  int b = bid >> 7, blk = bid & (NPB - 1);
  int t = threadIdx.x, w = t >> 6, lane = t & 63;

  // ---------------- P1: partial Gram via MFMA ----------------
  {
    const float* xb = x + (size_t)b * (BN * 64) + (size_t)blk * (64 * 64);
    int wi = w >> 1, wj = w & 1;
    int rr = t >> 2, cgp = t & 3;

    const float4* src = (const float4*)(xb + (size_t)rr * 64 + cgp * 16);
    float4 v0 = src[0], v1 = src[1], v2 = src[2], v3 = src[3];
    float vv[16] = { v0.x, v0.y, v0.z, v0.w,  v1.x, v1.y, v1.z, v1.w,
                     v2.x, v2.y, v2.z, v2.w,  v3.x, v3.y, v3.z, v3.w };
    #pragma unroll
    for (int j = 0; j < 16; ++j){
      sm.g.mred[t][j] = vv[j];
      sm.g.xT[cgp * 16 + j][rr] = (u16)f2b_u(vv[j]);
    }
    __syncthreads();

    f32x16 acc;
    #pragma unroll
    for (int i = 0; i < 16; ++i) acc[i] = 0.f;
    #pragma unroll
    for (int ks = 0; ks < 4; ++ks){
      int n0 = ks * 16 + (lane >> 5) * 8;
      short8 af = *(const short8*)&sm.g.xT[wi * 32 + (lane & 31)][n0];
      short8 bf = *(const short8*)&sm.g.xT[wj * 32 + (lane & 31)][n0];
      acc = __builtin_amdgcn_mfma_f32_32x32x16_bf16(af, bf, acc, 0, 0, 0);
    }

    float* dst = part + (size_t)bid * 4160;
    #pragma unroll
    for (int q = 0; q < 16; ++q){
      int grow = wi * 32 + (q & 3) + 8 * (q >> 2) + 4 * (lane >> 5);
      dst[grow * 64 + wj * 32 + (lane & 31)] = acc[q];
    }
    if (t < 64){
      int cgc = t >> 4, j = t & 15;
      float s0 = 0.f, s1 = 0.f, s2 = 0.f, s3 = 0.f;
      for (int ss = 0; ss < 64; ss += 4){
        s0 += sm.g.mred[cgc + 4 * ss][j];
        s1 += sm.g.mred[cgc + 4 * (ss + 1)][j];
        s2 += sm.g.mred[cgc + 4 * (ss + 2)][j];
        s3 += sm.g.mred[cgc + 4 * (ss + 3)][j];
      }
      dst[4096 + t] = (s0 + s1) + (s2 + s3);
    }
  }

  __threadfence();
  grid.sync();

  // ---------------- P2: reduceA (128 partials -> 8 group-partials) ----------
  {
    int tid = bid * 256 + t;
    for (int item = tid; item < 133120; item += 131072){
      int gg = item / 16640;
      int e  = item - gg * 16640;
      int bb = e / 4160, idx = e - bb * 4160;
      const float* pb = part + ((size_t)bb * NPB + gg * 16) * 4160 + idx;
      float s0 = 0.f, s1 = 0.f, s2 = 0.f, s3 = 0.f;
      #pragma unroll
      for (int p = 0; p < 16; p += 4){
        s0 += pb[(size_t)p * 4160];
        s1 += pb[(size_t)(p + 1) * 4160];
        s2 += pb[(size_t)(p + 2) * 4160];
        s3 += pb[(size_t)(p + 3) * 4160];
      }
      part2[item] = (s0 + s1) + (s2 + s3);
    }
  }

  __threadfence();
  grid.sync();

  // ---------------- P3: combine (blocks 0..3 only) ----------------
  if (bid < 4){
    int cb = bid;
    const float* Gb = part2 + (size_t)cb * 4160;
    for (int idx = t; idx < 4096; idx += 256){
      float s0 = 0.f, s1 = 0.f, s2 = 0.f, s3 = 0.f;
      #pragma unroll
      for (int g2 = 0; g2 < 8; g2 += 4){
        s0 += Gb[(size_t)g2 * 16640 + idx];
        s1 += Gb[(size_t)(g2 + 1) * 16640 + idx];
        s2 += Gb[(size_t)(g2 + 2) * 16640 + idx];
        s3 += Gb[(size_t)(g2 + 3) * 16640 + idx];
      }
      sm.c.Gt[(idx >> 6) * 68 + (idx & 63)] = (s0 + s1) + (s2 + s3);
    }
    if (t < 64){
      float s = 0.f;
      #pragma unroll
      for (int g2 = 0; g2 < 8; ++g2) s += Gb[(size_t)g2 * 16640 + 4096 + t];
      sm.c.Gt[64 * 68 + t] = s;
      sm.c.Gt[t * 68 + 64] = s;
    }
    if (t == 0) sm.c.Gt[64 * 68 + 64] = (float)BN;
    __syncthreads();

    {
      float gcol[65];
      #pragma unroll
      for (int a = 0; a < 65; ++a) gcol[a] = sm.c.Gt[a * 68 + lane];
      for (int i = w * 16; i < w * 16 + 16; ++i){
        float s0 = 0.f, s1 = 0.f, s2 = 0.f, s3 = 0.f;
        #pragma unroll
        for (int a = 0; a < 64; a += 4){
          s0 = fmaf(Wk[i * 64 + a],     gcol[a],     s0);
          s1 = fmaf(Wk[i * 64 + a + 1], gcol[a + 1], s1);
          s2 = fmaf(Wk[i * 64 + a + 2], gcol[a + 2], s2);
          s3 = fmaf(Wk[i * 64 + a + 3], gcol[a + 3], s3);
        }
        sm.c.Tl[i * 68 + lane] = ((s0 + s1) + (s2 + s3)) + bk[i] * gcol[64];
      }
    }
    if (w == 0){
      float s = 0.f;
      for (int a = 0; a < 64; ++a)
        s = fmaf(Wk[lane * 64 + a], sm.c.Gt[a * 68 + 64], s);
      s = fmaf(bk[lane], (float)BN, s);
      sm.c.Tl[lane * 68 + 64] = s;
    }
    __syncthreads();

    {
      float wv[65];
      const float4* Wv4 = (const float4*)(Wv + (size_t)lane * 64);
      #pragma unroll
      for (int c4 = 0; c4 < 16; ++c4){
        float4 vv = Wv4[c4];
        wv[4*c4] = vv.x; wv[4*c4+1] = vv.y; wv[4*c4+2] = vv.z; wv[4*c4+3] = vv.w;
      }
      wv[64] = bv[lane];
      for (int i = w * 16; i < w * 16 + 16; ++i){
        const float4* Tr = (const float4*)&sm.c.Tl[i * 68];
        float s0 = 0.f, s1 = 0.f, s2 = 0.f, s3 = 0.f;
        #pragma unroll
        for (int cc = 0; cc < 16; ++cc){
          float4 tv = Tr[cc];
          s0 = fmaf(tv.x, wv[4*cc],     s0);
          s1 = fmaf(tv.y, wv[4*cc + 1], s1);
          s2 = fmaf(tv.z, wv[4*cc + 2], s2);
          s3 = fmaf(tv.w, wv[4*cc + 3], s3);
        }
        sm.c.St[lane * 68 + i] = ((s0 + s1) + (s2 + s3))
                                 + sm.c.Tl[i * 68 + 64] * wv[64];
      }
    }
    __syncthreads();

    {
      const float inv = 1.0f / 65536.0f;
      float wq[64];
      #pragma unroll
      for (int i = 0; i < 64; ++i) wq[i] = Wq[i * 64 + lane];
      float* Mb = Mt + (size_t)cb * 4160;
      for (int d = w * 16; d < w * 16 + 16; ++d){
        const float4* Sr = (const float4*)&sm.c.St[d * 68];
        float s0 = 0.f, s1 = 0.f, s2 = 0.f, s3 = 0.f;
        #pragma unroll
        for (int ii = 0; ii < 16; ++ii){
          float4 sv = Sr[ii];
          s0 = fmaf(sv.x, wq[4*ii],     s0);
          s1 = fmaf(sv.y, wq[4*ii + 1], s1);
          s2 = fmaf(sv.z, wq[4*ii + 2], s2);
          s3 = fmaf(sv.w, wq[4*ii + 3], s3);
        }
        Mb[d * 65 + lane] = fmaf(inv, (s0 + s1) + (s2 + s3), Ww[d * 64 + lane]);
      }
      if (w == 0){
        float s = 0.f;
        for (int i = 0; i < 64; ++i) s = fmaf(sm.c.St[lane * 68 + i], bq[i], s);
        Mb[lane * 65 + 64] = fmaf(inv, s, bw[lane]);
      }
    }
  }

  __threadfence();
  grid.sync();

  // ---------------- P4: out = gelu(M~ x~) for this block's 64 rows ----------
  {
    int row = blk * 64 + lane;
    const float4* xr4 = (const float4*)(x + ((size_t)b * BN + row) * 64);
    float xv[64];
    #pragma unroll
    for (int q = 0; q < 16; ++q){
      float4 u = xr4[q];
      xv[4*q] = u.x; xv[4*q+1] = u.y; xv[4*q+2] = u.z; xv[4*q+3] = u.w;
    }
    const float* Mb = Mt + (size_t)b * 4160;
    float* orow = out + ((size_t)b * BN + row) * 64;

    #pragma unroll 1
    for (int dd = 0; dd < 8; ++dd){
      int d0 = w * 16 + 2 * dd, d1 = d0 + 1;
      float a0 = Mb[d0 * 65 + 64];
      float a1 = Mb[d1 * 65 + 64];
      #pragma unroll
      for (int c = 0; c < 64; ++c){
        a0 = fmaf(Mb[d0 * 65 + c], xv[c], a0);
        a1 = fmaf(Mb[d1 * 65 + c], xv[c], a1);
      }
      a0 = gelu_exact(a0);
      a1 = gelu_exact(a1);
      *(float2*)&orow[d0] = make_float2(a0, a1);
    }
  }
}

// ===========================================================================
// FALLBACK chain (round-7, known-good, 73.1 us)
// ===========================================================================
__global__ __launch_bounds__(256) void k_gram(const float* __restrict__ x,
                                              float* __restrict__ part){
  int bid = blockIdx.x;
  int b = bid >> 7, blk = bid & (NPB - 1);
  int t = threadIdx.x, w = t >> 6, lane = t & 63;
  const float* xb = x + (size_t)b * BN * 64 + (size_t)blk * 64 * 64;

  __shared__ __align__(16) u16 xT[64][72];
  __shared__ float mred[256][16];

  int wi = w >> 1, wj = w & 1;
  int r = t >> 2, cg = t & 3;

  const float4* src = (const float4*)(xb + (size_t)r * 64 + cg * 16);
  float4 v0 = src[0], v1 = src[1], v2 = src[2], v3 = src[3];
  float vv[16] = { v0.x, v0.y, v0.z, v0.w,  v1.x, v1.y, v1.z, v1.w,
                   v2.x, v2.y, v2.z, v2.w,  v3.x, v3.y, v3.z, v3.w };
  #pragma unroll
  for (int j = 0; j < 16; ++j){
    mred[t][j] = vv[j];
    xT[cg * 16 + j][r] = (u16)f2b_u(vv[j]);
  }
  __syncthreads();

  f32x16 acc;
  #pragma unroll
  for (int i = 0; i < 16; ++i) acc[i] = 0.f;
  #pragma unroll
  for (int ks = 0; ks < 4; ++ks){
    int n0 = ks * 16 + (lane >> 5) * 8;
    short8 af = *(const short8*)&xT[wi * 32 + (lane & 31)][n0];
    short8 bf = *(const short8*)&xT[wj * 32 + (lane & 31)][n0];
    acc = __builtin_amdgcn_mfma_f32_32x32x16_bf16(af, bf, acc, 0, 0, 0);
  }

  float* dst = part + (size_t)bid * 4160;
  #pragma unroll
  for (int rr = 0; rr < 16; ++rr){
    int grow = wi * 32 + (rr & 3) + 8 * (rr >> 2) + 4 * (lane >> 5);
    dst[grow * 64 + wj * 32 + (lane & 31)] = acc[rr];
  }

  if (t < 64){
    int cgc = t >> 4, j = t & 15;
    float s0 = 0.f, s1 = 0.f, s2 = 0.f, s3 = 0.f;
    for (int ss = 0; ss < 64; ss += 4){
      s0 += mred[cgc + 4 * ss][j];
      s1 += mred[cgc + 4 * (ss + 1)][j];
      s2 += mred[cgc + 4 * (ss + 2)][j];
      s3 += mred[cgc + 4 * (ss + 3)][j];
    }
    dst[4096 + t] = (s0 + s1) + (s2 + s3);
  }
}

__global__ __launch_bounds__(256) void k_reduceA(const float* __restrict__ part,
                                                 float* __restrict__ part2){
  int g = blockIdx.x / 65, c = blockIdx.x - g * 65;
  int e = c * 256 + threadIdx.x;
  int b = e / 4160, idx = e - b * 4160;
  const float* pb = part + ((size_t)b * NPB + g * 16) * 4160 + idx;
  float s0 = 0.f, s1 = 0.f, s2 = 0.f, s3 = 0.f;
  #pragma unroll
  for (int p = 0; p < 16; p += 4){
    s0 += pb[(size_t)p * 4160];
    s1 += pb[(size_t)(p + 1) * 4160];
    s2 += pb[(size_t)(p + 2) * 4160];
    s3 += pb[(size_t)(p + 3) * 4160];
  }
  part2[(size_t)g * 16640 + e] = (s0 + s1) + (s2 + s3);
}

__global__ __launch_bounds__(512) void k_combine(
    const float* __restrict__ part2,
    const float* __restrict__ Wq, const float* __restrict__ bq,
    const float* __restrict__ Wk, const float* __restrict__ bk,
    const float* __restrict__ Wv, const float* __restrict__ bv,
    const float* __restrict__ Ww, const float* __restrict__ bw,
    float* __restrict__ Mt){
  int b = blockIdx.x;
  int t = threadIdx.x, w = t >> 6, lane = t & 63;

  __shared__ __align__(16) float Gt[65 * 68];
  __shared__ __align__(16) float Tl[64 * 68];
  __shared__ __align__(16) float St[64 * 68];

  const float* Gb = part2 + (size_t)b * 4160;
  for (int idx = t; idx < 4096; idx += 512){
    float s0 = 0.f, s1 = 0.f, s2 = 0.f, s3 = 0.f;
    #pragma unroll
    for (int g = 0; g < 8; g += 4){
      s0 += Gb[(size_t)g * 16640 + idx];
      s1 += Gb[(size_t)(g + 1) * 16640 + idx];
      s2 += Gb[(size_t)(g + 2) * 16640 + idx];
      s3 += Gb[(size_t)(g + 3) * 16640 + idx];
    }
    Gt[(idx >> 6) * 68 + (idx & 63)] = (s0 + s1) + (s2 + s3);
  }
  if (t < 64){
    float s = 0.f;
    #pragma unroll
    for (int g = 0; g < 8; ++g) s += Gb[(size_t)g * 16640 + 4096 + t];
    Gt[64 * 68 + t] = s;
    Gt[t * 68 + 64] = s;
  }
  if (t == 0) Gt[64 * 68 + 64] = (float)BN;
  __syncthreads();

  {
    float gcol[65];
    #pragma unroll
    for (int a = 0; a < 65; ++a) gcol[a] = Gt[a * 68 + lane];
    for (int i = w * 8; i < w * 8 + 8; ++i){
      float s0 = 0.f, s1 = 0.f, s2 = 0.f, s3 = 0.f;
      #pragma unroll
      for (int a = 0; a < 64; a += 4){
        s0 = fmaf(Wk[i * 64 + a],     gcol[a],     s0);
        s1 = fmaf(Wk[i * 64 + a + 1], gcol[a + 1], s1);
        s2 = fmaf(Wk[i * 64 + a + 2], gcol[a + 2], s2);
        s3 = fmaf(Wk[i * 64 + a + 3], gcol[a + 3], s3);
      }
      Tl[i * 68 + lane] = ((s0 + s1) + (s2 + s3)) + bk[i] * gcol[64];
    }
  }
  if (w == 0){
    float s = 0.f;
    for (int a = 0; a < 64; ++a) s = fmaf(Wk[lane * 64 + a], Gt[a * 68 + 64], s);
    s = fmaf(bk[lane], (float)BN, s);
    Tl[lane * 68 + 64] = s;
  }
  __syncthreads();

  {
    float wv[65];
    const float4* Wv4 = (const float4*)(Wv + (size_t)lane * 64);
    #pragma unroll
    for (int c4 = 0; c4 < 16; ++c4){
      float4 vv = Wv4[c4];
      wv[4*c4] = vv.x; wv[4*c4+1] = vv.y; wv[4*c4+2] = vv.z; wv[4*c4+3] = vv.w;
    }
    wv[64] = bv[lane];
    for (int i = w * 8; i < w * 8 + 8; ++i){
      const float4* Tr = (const float4*)&Tl[i * 68];
      float s0 = 0.f, s1 = 0.f, s2 = 0.f, s3 = 0.f;
      #pragma unroll
      for (int cc = 0; cc < 16; ++cc){
        float4 tv = Tr[cc];
        s0 = fmaf(tv.x, wv[4*cc],     s0);
        s1 = fmaf(tv.y, wv[4*cc + 1], s1);
        s2 = fmaf(tv.z, wv[4*cc + 2], s2);
        s3 = fmaf(tv.w, wv[4*cc + 3], s3);
      }
      St[lane * 68 + i] = ((s0 + s1) + (s2 + s3)) + Tl[i * 68 + 64] * wv[64];
    }
  }
  __syncthreads();

  {
    const float inv = 1.0f / 65536.0f;
    float wq[64];
    #pragma unroll
    for (int i = 0; i < 64; ++i) wq[i] = Wq[i * 64 + lane];
    float* Mb = Mt + (size_t)b * 4160;
    for (int d = w * 8; d < w * 8 + 8; ++d){
      const float4* Sr = (const float4*)&St[d * 68];
      float s0 = 0.f, s1 = 0.f, s2 = 0.f, s3 = 0.f;
      #pragma unroll
      for (int ii = 0; ii < 16; ++ii){
        float4 sv = Sr[ii];
        s0 = fmaf(sv.x, wq[4*ii],     s0);
        s1 = fmaf(sv.y, wq[4*ii + 1], s1);
        s2 = fmaf(sv.z, wq[4*ii + 2], s2);
        s3 = fmaf(sv.w, wq[4*ii + 3], s3);
      }
      Mb[d * 65 + lane] = fmaf(inv, (s0 + s1) + (s2 + s3), Ww[d * 64 + lane]);
    }
    if (w == 0){
      float s = 0.f;
      for (int i = 0; i < 64; ++i) s = fmaf(St[lane * 68 + i], bq[i], s);
      Mb[lane * 65 + 64] = fmaf(inv, s, bw[lane]);
    }
  }
}

__global__ __launch_bounds__(256) void k_out(const float* __restrict__ x,
                                             const float* __restrict__ Mt,
                                             float* __restrict__ out){
  int bid = blockIdx.x;
  int b = bid >> 6, blk = bid & 63;
  int t = threadIdx.x, w = t >> 6, lane = t & 63;
  int h = w & 1, dh = w >> 1;
  int r0 = blk * 128 + h * 64;
  int row = r0 + lane;

  const float4* xr4 = (const float4*)(x + ((size_t)(b * BN + row)) * 64);
  float xv[64];
  #pragma unroll
  for (int q = 0; q < 16; ++q){
    float4 u = xr4[q];
    xv[4*q] = u.x; xv[4*q+1] = u.y; xv[4*q+2] = u.z; xv[4*q+3] = u.w;
  }

  __shared__ __align__(16) float tp[4][64 * 34];
  float* tpw = &tp[w][0];
  const float* Mb = Mt + (size_t)b * 4160;

  #pragma unroll 1
  for (int dd = 0; dd < 16; ++dd){
    int d0 = dh * 32 + 2 * dd, d1 = d0 + 1;
    float a0 = Mb[d0 * 65 + 64];
    float a1 = Mb[d1 * 65 + 64];
    #pragma unroll
    for (int c = 0; c < 64; ++c){
      a0 = fmaf(Mb[d0 * 65 + c], xv[c], a0);
      a1 = fmaf(Mb[d1 * 65 + c], xv[c], a1);
    }
    a0 = gelu_exact(a0);
    a1 = gelu_exact(a1);
    *(float2*)&tpw[lane * 34 + 2 * dd] = make_float2(a0, a1);
  }
  __syncthreads();

  #pragma unroll 1
  for (int rr = 0; rr < 16; ++rr){
    int rloc = rr * 4 + (lane >> 4);
    int p = lane & 15;
    float2 v = *(const float2*)&tpw[rloc * 34 + 2 * p];
    float* dst = out + ((size_t)(b * BN + r0 + rloc)) * 64 + dh * 32 + 2 * p;
    *(float2*)dst = v;
  }
}

// ---------------------------------------------------------------------------
extern "C" void kernel_launch(void* const* d_in, const int* in_sizes, int n_in,
                              void* d_out, int out_size, void* d_ws, size_t ws_size,
                              hipStream_t stream) {
  const float* x  = (const float*)d_in[0];
  const float* Wq = (const float*)d_in[1];
  const float* bq = (const float*)d_in[2];
  const float* Wk = (const float*)d_in[3];
  const float* bk = (const float*)d_in[4];
  const float* Wv = (const float*)d_in[5];
  const float* bv = (const float*)d_in[6];
  const float* Ww = (const float*)d_in[7];
  const float* bw = (const float*)d_in[8];
  float* out = (float*)d_out;

  float* ws    = (float*)d_ws;
  float* Mt    = ws;             // 4*4160   = 16640 floats
  float* part2 = ws + 16640;     // 8*16640  = 133120 floats
  float* part  = ws + 149760;    // 512*4160 = 2129920 floats (~8.5 MB)

  // --- try cooperative fused path; fall back to the 4-kernel chain ---
  bool launched = false;
  int dev = 0, coop = 0;
  if (hipGetDevice(&dev) == hipSuccess &&
      hipDeviceGetAttribute(&coop, hipDeviceAttributeCooperativeLaunch, dev)
        == hipSuccess && coop){
    void* args[] = {
      (void*)&x,
      (void*)&Wq, (void*)&bq, (void*)&Wk, (void*)&bk,
      (void*)&Wv, (void*)&bv, (void*)&Ww, (void*)&bw,
      (void*)&part, (void*)&part2, (void*)&Mt, (void*)&out
    };
    hipError_t e = hipLaunchCooperativeKernel((const void*)k_fused,
                                              dim3(512), dim3(256),
                                              args, 0, stream);
    if (e == hipSuccess) launched = true;
    else (void)hipGetLastError();   // clear sticky error, take fallback
  }

  if (!launched){
    k_gram   <<<dim3(4 * NPB), 256, 0, stream>>>(x, part);
    k_reduceA<<<dim3(520),     256, 0, stream>>>(part, part2);
    k_combine<<<dim3(4),       512, 0, stream>>>(part2, Wq, bq, Wk, bk,
                                                 Wv, bv, Ww, bw, Mt);
    k_out    <<<dim3(256),     256, 0, stream>>>(x, Mt, out);
  }
}

// Round 10
// 51.304 us; speedup vs baseline: 7.3969x; 7.3969x over previous
//
#include <hip/hip_runtime.h>
#include <stdint.h>

typedef unsigned int u32;
typedef unsigned short u16;
typedef short short8 __attribute__((ext_vector_type(8)));
typedef float f32x16 __attribute__((ext_vector_type(16)));

#define BN 8192
#define NPB 32            // partial tiles per batch (256 rows each)
#define NT 4              // 64-row subtiles per gram block

__device__ __forceinline__ u32 f2b_u(float f){
  u32 x = __float_as_uint(f);
  return (x + 0x7fffu + ((x >> 16) & 1u)) >> 16;   // RNE f32->bf16
}
__device__ __forceinline__ float gelu_exact(float v){
  return 0.5f * v * (1.0f + erff(v * 0.70710678118654752440f));
}

// ---------------------------------------------------------------------------
// K1: per-block partial Gram via MFMA. 256 rows per block (4 subtiles of 64).
// grid = 4*NPB = 128 blocks, 256 threads.
// partial layout per block: 4096 floats G[i][j] + 64 floats m[j].
// ---------------------------------------------------------------------------
__global__ __launch_bounds__(256) void k_gram(const float* __restrict__ x,
                                              float* __restrict__ part){
  int bid = blockIdx.x;
  int b = bid >> 5, blk = bid & (NPB - 1);
  int t = threadIdx.x, w = t >> 6, lane = t & 63;
  const float* xb = x + (size_t)b * BN * 64 + (size_t)blk * 256 * 64;

  __shared__ __align__(16) u16 xT[64][72];     // [col][row] bf16, pad 72
  __shared__ float mred[256][16];

  int wi = w >> 1, wj = w & 1;                 // wave's G quadrant
  int r = t >> 2, cg = t & 3;                  // staging: row r, col-group cg

  f32x16 acc;
  #pragma unroll
  for (int i = 0; i < 16; ++i) acc[i] = 0.f;
  float macc[16];
  #pragma unroll
  for (int j = 0; j < 16; ++j) macc[j] = 0.f;

  for (int tile = 0; tile < NT; ++tile){
    const float4* src = (const float4*)(xb + ((size_t)(tile * 64 + r)) * 64 + cg * 16);
    float4 v0 = src[0], v1 = src[1], v2 = src[2], v3 = src[3];
    float vv[16] = { v0.x, v0.y, v0.z, v0.w,  v1.x, v1.y, v1.z, v1.w,
                     v2.x, v2.y, v2.z, v2.w,  v3.x, v3.y, v3.z, v3.w };
    #pragma unroll
    for (int j = 0; j < 16; ++j){
      macc[j] += vv[j];
      xT[cg * 16 + j][r] = (u16)f2b_u(vv[j]);
    }
    __syncthreads();

    #pragma unroll
    for (int ks = 0; ks < 4; ++ks){
      int n0 = ks * 16 + (lane >> 5) * 8;
      short8 af = *(const short8*)&xT[wi * 32 + (lane & 31)][n0];
      short8 bf = *(const short8*)&xT[wj * 32 + (lane & 31)][n0];
      acc = __builtin_amdgcn_mfma_f32_32x32x16_bf16(af, bf, acc, 0, 0, 0);
    }
    __syncthreads();   // before next tile overwrites xT
  }

  // C/D map: col = lane&31, row = (reg&3) + 8*(reg>>2) + 4*(lane>>5)
  float* dst = part + (size_t)bid * 4160;
  #pragma unroll
  for (int q = 0; q < 16; ++q){
    int grow = wi * 32 + (q & 3) + 8 * (q >> 2) + 4 * (lane >> 5);
    dst[grow * 64 + wj * 32 + (lane & 31)] = acc[q];
  }

  #pragma unroll
  for (int j = 0; j < 16; ++j) mred[t][j] = macc[j];
  __syncthreads();
  if (t < 64){
    int cgc = t >> 4, j = t & 15;
    float s0 = 0.f, s1 = 0.f, s2 = 0.f, s3 = 0.f;
    for (int ss = 0; ss < 64; ss += 4){
      s0 += mred[cgc + 4 * ss][j];
      s1 += mred[cgc + 4 * (ss + 1)][j];
      s2 += mred[cgc + 4 * (ss + 2)][j];
      s3 += mred[cgc + 4 * (ss + 3)][j];
    }
    dst[4096 + t] = (s0 + s1) + (s2 + s3);
  }
}

// ---------------------------------------------------------------------------
// K2: everything else, fused per block. grid = 64 blocks (16/batch), 512 thr.
//  A: sum 32 partials -> Gt (LDS)
//  B: T = W~k G~    C: St = S^T    D: M~ -> LDS bf16 (+ fp32 bias col)
//  E: out = gelu(x~ M~^T) via MFMA over 4 x 128-row groups, direct stores.
// ---------------------------------------------------------------------------
union SM2 {
  struct { float Gt[65*68]; float Tl[64*68]; float St[64*68]; } c;  // 52.5 KB
  struct { u16 Mb16[64][72]; float Mbias[72]; u16 xR[128][72]; } o; // 27.9 KB
};

__global__ __launch_bounds__(512) void k_fused2(
    const float* __restrict__ x, const float* __restrict__ part,
    const float* __restrict__ Wq, const float* __restrict__ bq,
    const float* __restrict__ Wk, const float* __restrict__ bk,
    const float* __restrict__ Wv, const float* __restrict__ bv,
    const float* __restrict__ Ww, const float* __restrict__ bw,
    float* __restrict__ out)
{
  __shared__ SM2 sm;
  int bid = blockIdx.x;
  int b = bid >> 4, blk = bid & 15;
  int t = threadIdx.x, w = t >> 6, lane = t & 63;

  // ---- A: Gram assembly (sum the batch's 32 partials) ----
  {
    const float* pb = part + (size_t)b * NPB * 4160;
    #pragma unroll 2
    for (int idx = t; idx < 4096; idx += 512){
      float s0 = 0.f, s1 = 0.f, s2 = 0.f, s3 = 0.f;
      #pragma unroll
      for (int p = 0; p < NPB; p += 4){
        s0 += pb[(size_t)p * 4160 + idx];
        s1 += pb[(size_t)(p + 1) * 4160 + idx];
        s2 += pb[(size_t)(p + 2) * 4160 + idx];
        s3 += pb[(size_t)(p + 3) * 4160 + idx];
      }
      sm.c.Gt[(idx >> 6) * 68 + (idx & 63)] = (s0 + s1) + (s2 + s3);
    }
    if (t < 64){
      float s0 = 0.f, s1 = 0.f, s2 = 0.f, s3 = 0.f;
      #pragma unroll
      for (int p = 0; p < NPB; p += 4){
        s0 += pb[(size_t)p * 4160 + 4096 + t];
        s1 += pb[(size_t)(p + 1) * 4160 + 4096 + t];
        s2 += pb[(size_t)(p + 2) * 4160 + 4096 + t];
        s3 += pb[(size_t)(p + 3) * 4160 + 4096 + t];
      }
      float m = (s0 + s1) + (s2 + s3);
      sm.c.Gt[64 * 68 + t] = m;
      sm.c.Gt[t * 68 + 64] = m;
    }
    if (t == 0) sm.c.Gt[64 * 68 + 64] = (float)BN;
  }
  __syncthreads();

  // ---- B: T[i][c] = sum_a W~k[i][a] G~[a][c], c = lane; 8 rows/wave ----
  {
    float gcol[65];
    #pragma unroll
    for (int a = 0; a < 65; ++a) gcol[a] = sm.c.Gt[a * 68 + lane];
    for (int i = w * 8; i < w * 8 + 8; ++i){
      float s0 = 0.f, s1 = 0.f, s2 = 0.f, s3 = 0.f;
      #pragma unroll
      for (int a = 0; a < 64; a += 4){
        s0 = fmaf(Wk[i * 64 + a],     gcol[a],     s0);
        s1 = fmaf(Wk[i * 64 + a + 1], gcol[a + 1], s1);
        s2 = fmaf(Wk[i * 64 + a + 2], gcol[a + 2], s2);
        s3 = fmaf(Wk[i * 64 + a + 3], gcol[a + 3], s3);
      }
      sm.c.Tl[i * 68 + lane] = ((s0 + s1) + (s2 + s3)) + bk[i] * gcol[64];
    }
  }
  if (w == 0){   // column 64 of T, lane = i
    float s = 0.f;
    for (int a = 0; a < 64; ++a)
      s = fmaf(Wk[lane * 64 + a], sm.c.Gt[a * 68 + 64], s);
    s = fmaf(bk[lane], (float)BN, s);
    sm.c.Tl[lane * 68 + 64] = s;
  }
  __syncthreads();

  // ---- C: St[j][i] = S[i][j] = sum_c T[i][c] W~v[j][c], j = lane ----
  {
    float wv[65];
    const float4* Wv4 = (const float4*)(Wv + (size_t)lane * 64);
    #pragma unroll
    for (int c4 = 0; c4 < 16; ++c4){
      float4 vv = Wv4[c4];
      wv[4*c4] = vv.x; wv[4*c4+1] = vv.y; wv[4*c4+2] = vv.z; wv[4*c4+3] = vv.w;
    }
    wv[64] = bv[lane];
    for (int i = w * 8; i < w * 8 + 8; ++i){
      const float4* Tr = (const float4*)&sm.c.Tl[i * 68];
      float s0 = 0.f, s1 = 0.f, s2 = 0.f, s3 = 0.f;
      #pragma unroll
      for (int cc = 0; cc < 16; ++cc){
        float4 tv = Tr[cc];
        s0 = fmaf(tv.x, wv[4*cc],     s0);
        s1 = fmaf(tv.y, wv[4*cc + 1], s1);
        s2 = fmaf(tv.z, wv[4*cc + 2], s2);
        s3 = fmaf(tv.w, wv[4*cc + 3], s3);
      }
      sm.c.St[lane * 68 + i] = ((s0 + s1) + (s2 + s3))
                               + sm.c.Tl[i * 68 + 64] * wv[64];
    }
  }
  __syncthreads();

  // ---- D: M~[d][c] -> LDS bf16; bias col fp32 (writes overlay Gt region) ---
  {
    const float inv = 1.0f / 65536.0f;   // 1/(sqrt(64)*8192)
    float wq[64];
    #pragma unroll
    for (int i = 0; i < 64; ++i) wq[i] = Wq[i * 64 + lane];   // column c = lane
    for (int d = w * 8; d < w * 8 + 8; ++d){
      const float4* Sr = (const float4*)&sm.c.St[d * 68];
      float s0 = 0.f, s1 = 0.f, s2 = 0.f, s3 = 0.f;
      #pragma unroll
      for (int ii = 0; ii < 16; ++ii){
        float4 sv = Sr[ii];
        s0 = fmaf(sv.x, wq[4*ii],     s0);
        s1 = fmaf(sv.y, wq[4*ii + 1], s1);
        s2 = fmaf(sv.z, wq[4*ii + 2], s2);
        s3 = fmaf(sv.w, wq[4*ii + 3], s3);
      }
      float val = fmaf(inv, (s0 + s1) + (s2 + s3), Ww[d * 64 + lane]);
      sm.o.Mb16[d][lane] = (u16)f2b_u(val);
    }
    if (w == 0){   // affine-const column, lane = d (St untouched by D writes)
      float s = 0.f;
      for (int i = 0; i < 64; ++i) s = fmaf(sm.c.St[lane * 68 + i], bq[i], s);
      sm.o.Mbias[lane] = fmaf(inv, s, bw[lane]);
    }
  }
  __syncthreads();

  // ---- E: out = gelu(x~ M~^T) via MFMA; 4 iterations x 128 rows ----
  {
    const float* xb = x + (size_t)b * BN * 64;
    int wd = w & 1, wn = (w >> 1) & 1, gq = w >> 2;   // quadrant assignment
    int r2 = t >> 2, cg = t & 3;                      // staging: row, col-group

    for (int it = 0; it < 4; ++it){
      int rowbase = blk * 512 + it * 128;
      // stage 128 rows row-major bf16 (pairs packed to u32 writes)
      const float4* src = (const float4*)(xb + (size_t)(rowbase + r2) * 64 + cg * 16);
      float4 v0 = src[0], v1 = src[1], v2 = src[2], v3 = src[3];
      float vv[16] = { v0.x, v0.y, v0.z, v0.w,  v1.x, v1.y, v1.z, v1.w,
                       v2.x, v2.y, v2.z, v2.w,  v3.x, v3.y, v3.z, v3.w };
      #pragma unroll
      for (int j = 0; j < 8; ++j){
        u32 pk = f2b_u(vv[2*j]) | (f2b_u(vv[2*j+1]) << 16);
        *(u32*)&sm.o.xR[r2][cg * 16 + 2*j] = pk;
      }
      __syncthreads();

      f32x16 oacc;
      #pragma unroll
      for (int i = 0; i < 16; ++i) oacc[i] = 0.f;
      #pragma unroll
      for (int ks = 0; ks < 4; ++ks){
        int c0 = ks * 16 + (lane >> 5) * 8;
        short8 af = *(const short8*)&sm.o.xR [gq * 64 + wn * 32 + (lane & 31)][c0];
        short8 bf = *(const short8*)&sm.o.Mb16[wd * 32 + (lane & 31)][c0];
        oacc = __builtin_amdgcn_mfma_f32_32x32x16_bf16(af, bf, oacc, 0, 0, 0);
      }
      float bias = sm.o.Mbias[wd * 32 + (lane & 31)];
      int d = wd * 32 + (lane & 31);
      #pragma unroll
      for (int q = 0; q < 16; ++q){
        int n = rowbase + gq * 64 + wn * 32
              + (q & 3) + 8 * (q >> 2) + 4 * (lane >> 5);
        out[((size_t)b * BN + n) * 64 + d] = gelu_exact(oacc[q] + bias);
      }
      __syncthreads();   // before next iteration overwrites xR
    }
  }
}

// ---------------------------------------------------------------------------
extern "C" void kernel_launch(void* const* d_in, const int* in_sizes, int n_in,
                              void* d_out, int out_size, void* d_ws, size_t ws_size,
                              hipStream_t stream) {
  const float* x  = (const float*)d_in[0];
  const float* Wq = (const float*)d_in[1];
  const float* bq = (const float*)d_in[2];
  const float* Wk = (const float*)d_in[3];
  const float* bk = (const float*)d_in[4];
  const float* Wv = (const float*)d_in[5];
  const float* bv = (const float*)d_in[6];
  const float* Ww = (const float*)d_in[7];
  const float* bw = (const float*)d_in[8];
  float* out = (float*)d_out;

  float* part = (float*)d_ws;    // 128 * 4160 floats (~2.13 MB)

  k_gram  <<<dim3(4 * NPB), 256, 0, stream>>>(x, part);
  k_fused2<<<dim3(64),      512, 0, stream>>>(x, part, Wq, bq, Wk, bk,
                                              Wv, bv, Ww, bw, out);
}

// Round 12
// 41.625 us; speedup vs baseline: 9.1169x; 1.2325x over previous
//
#include <hip/hip_runtime.h>
#include <stdint.h>

typedef unsigned int u32;
typedef unsigned short u16;
typedef short short8 __attribute__((ext_vector_type(8)));
typedef float f32x16 __attribute__((ext_vector_type(16)));

#define BN 8192
#define NPB 32            // partial tiles per batch (256 rows each)
#define NT 4              // 64-row subtiles per gram block

__device__ __forceinline__ u32 f2b_u(float f){
  u32 x = __float_as_uint(f);
  return (x + 0x7fffu + ((x >> 16) & 1u)) >> 16;   // RNE f32->bf16
}
__device__ __forceinline__ float gelu_exact(float v){
  return 0.5f * v * (1.0f + erff(v * 0.70710678118654752440f));
}
__device__ __forceinline__ void add4(float4& a, const float4 b){
  a.x += b.x; a.y += b.y; a.z += b.z; a.w += b.w;
}

// ---------------------------------------------------------------------------
// K1: per-block partial Gram via MFMA. 256 rows per block (4 subtiles of 64).
// grid = 4*NPB = 128 blocks, 256 threads. (r10-proven)
// partial layout per block: 4096 floats G[i][j] + 64 floats m[j].
// ---------------------------------------------------------------------------
__global__ __launch_bounds__(256) void k_gram(const float* __restrict__ x,
                                              float* __restrict__ part){
  int bid = blockIdx.x;
  int b = bid >> 5, blk = bid & (NPB - 1);
  int t = threadIdx.x, w = t >> 6, lane = t & 63;
  const float* xb = x + (size_t)b * BN * 64 + (size_t)blk * 256 * 64;

  __shared__ __align__(16) u16 xT[64][72];     // [col][row] bf16, pad 72
  __shared__ float mred[256][16];

  int wi = w >> 1, wj = w & 1;
  int r = t >> 2, cg = t & 3;

  f32x16 acc;
  #pragma unroll
  for (int i = 0; i < 16; ++i) acc[i] = 0.f;
  float macc[16];
  #pragma unroll
  for (int j = 0; j < 16; ++j) macc[j] = 0.f;

  for (int tile = 0; tile < NT; ++tile){
    const float4* src = (const float4*)(xb + ((size_t)(tile * 64 + r)) * 64 + cg * 16);
    float4 v0 = src[0], v1 = src[1], v2 = src[2], v3 = src[3];
    float vv[16] = { v0.x, v0.y, v0.z, v0.w,  v1.x, v1.y, v1.z, v1.w,
                     v2.x, v2.y, v2.z, v2.w,  v3.x, v3.y, v3.z, v3.w };
    #pragma unroll
    for (int j = 0; j < 16; ++j){
      macc[j] += vv[j];
      xT[cg * 16 + j][r] = (u16)f2b_u(vv[j]);
    }
    __syncthreads();

    #pragma unroll
    for (int ks = 0; ks < 4; ++ks){
      int n0 = ks * 16 + (lane >> 5) * 8;
      short8 af = *(const short8*)&xT[wi * 32 + (lane & 31)][n0];
      short8 bf = *(const short8*)&xT[wj * 32 + (lane & 31)][n0];
      acc = __builtin_amdgcn_mfma_f32_32x32x16_bf16(af, bf, acc, 0, 0, 0);
    }
    __syncthreads();
  }

  // C/D map: col = lane&31, row = (reg&3) + 8*(reg>>2) + 4*(lane>>5)
  float* dst = part + (size_t)bid * 4160;
  #pragma unroll
  for (int q = 0; q < 16; ++q){
    int grow = wi * 32 + (q & 3) + 8 * (q >> 2) + 4 * (lane >> 5);
    dst[grow * 64 + wj * 32 + (lane & 31)] = acc[q];
  }

  #pragma unroll
  for (int j = 0; j < 16; ++j) mred[t][j] = macc[j];
  __syncthreads();
  if (t < 64){
    int cgc = t >> 4, j = t & 15;
    float s0 = 0.f, s1 = 0.f, s2 = 0.f, s3 = 0.f;
    for (int ss = 0; ss < 64; ss += 4){
      s0 += mred[cgc + 4 * ss][j];
      s1 += mred[cgc + 4 * (ss + 1)][j];
      s2 += mred[cgc + 4 * (ss + 2)][j];
      s3 += mred[cgc + 4 * (ss + 3)][j];
    }
    dst[4096 + t] = (s0 + s1) + (s2 + s3);
  }
}

// ---------------------------------------------------------------------------
// K2: per-batch combine, ONCE. grid = 4 blocks, 512 threads.
//  A: sum 32 partials (float4 loads, 4-way ILP) -> Gt (LDS)
//  B: T = W~k G~   C: St = S^T   D: M~ -> ws as bf16 [64][72] image + f32 bias
// ---------------------------------------------------------------------------
__global__ __launch_bounds__(512) void k_combine(
    const float* __restrict__ part,
    const float* __restrict__ Wq, const float* __restrict__ bq,
    const float* __restrict__ Wk, const float* __restrict__ bk,
    const float* __restrict__ Wv, const float* __restrict__ bv,
    const float* __restrict__ Ww, const float* __restrict__ bw,
    u16* __restrict__ Mws, float* __restrict__ biasws)
{
  int b = blockIdx.x;
  int t = threadIdx.x, w = t >> 6, lane = t & 63;

  __shared__ __align__(16) float Gt[65 * 68];
  __shared__ __align__(16) float Tl[64 * 68];
  __shared__ __align__(16) float St[64 * 68];

  // ---- A: Gram assembly, vectorized ----
  {
    const float4* pb4 = (const float4*)(part + (size_t)b * NPB * 4160);
    // G area: 1024 float4 per partial; partial stride 1040 float4.
    for (int g = t; g < 1024; g += 512){
      float4 s0 = make_float4(0,0,0,0), s1 = s0, s2 = s0, s3 = s0;
      #pragma unroll
      for (int p = 0; p < NPB; p += 4){
        add4(s0, pb4[(size_t)p * 1040 + g]);
        add4(s1, pb4[(size_t)(p + 1) * 1040 + g]);
        add4(s2, pb4[(size_t)(p + 2) * 1040 + g]);
        add4(s3, pb4[(size_t)(p + 3) * 1040 + g]);
      }
      add4(s0, s1); add4(s2, s3); add4(s0, s2);
      *(float4*)&Gt[(g >> 4) * 68 + (g & 15) * 4] = s0;
    }
    if (t < 64){
      const float* pm = part + (size_t)b * NPB * 4160 + 4096 + t;
      float s0 = 0.f, s1 = 0.f, s2 = 0.f, s3 = 0.f;
      #pragma unroll
      for (int p = 0; p < NPB; p += 4){
        s0 += pm[(size_t)p * 4160];
        s1 += pm[(size_t)(p + 1) * 4160];
        s2 += pm[(size_t)(p + 2) * 4160];
        s3 += pm[(size_t)(p + 3) * 4160];
      }
      float m = (s0 + s1) + (s2 + s3);
      Gt[64 * 68 + t] = m;
      Gt[t * 68 + 64] = m;
    }
    if (t == 0) Gt[64 * 68 + 64] = (float)BN;
  }
  __syncthreads();

  // ---- B: T[i][c] = sum_a W~k[i][a] G~[a][c], c = lane; 8 rows/wave ----
  {
    float gcol[65];
    #pragma unroll
    for (int a = 0; a < 65; ++a) gcol[a] = Gt[a * 68 + lane];
    for (int i = w * 8; i < w * 8 + 8; ++i){
      float s0 = 0.f, s1 = 0.f, s2 = 0.f, s3 = 0.f;
      #pragma unroll
      for (int a = 0; a < 64; a += 4){
        s0 = fmaf(Wk[i * 64 + a],     gcol[a],     s0);
        s1 = fmaf(Wk[i * 64 + a + 1], gcol[a + 1], s1);
        s2 = fmaf(Wk[i * 64 + a + 2], gcol[a + 2], s2);
        s3 = fmaf(Wk[i * 64 + a + 3], gcol[a + 3], s3);
      }
      Tl[i * 68 + lane] = ((s0 + s1) + (s2 + s3)) + bk[i] * gcol[64];
    }
  }
  if (w == 0){   // column 64 of T, lane = i
    float s = 0.f;
    for (int a = 0; a < 64; ++a)
      s = fmaf(Wk[lane * 64 + a], Gt[a * 68 + 64], s);
    s = fmaf(bk[lane], (float)BN, s);
    Tl[lane * 68 + 64] = s;
  }
  __syncthreads();

  // ---- C: St[j][i] = S[i][j] = sum_c T[i][c] W~v[j][c], j = lane ----
  {
    float wv[65];
    const float4* Wv4 = (const float4*)(Wv + (size_t)lane * 64);
    #pragma unroll
    for (int c4 = 0; c4 < 16; ++c4){
      float4 vv = Wv4[c4];
      wv[4*c4] = vv.x; wv[4*c4+1] = vv.y; wv[4*c4+2] = vv.z; wv[4*c4+3] = vv.w;
    }
    wv[64] = bv[lane];
    for (int i = w * 8; i < w * 8 + 8; ++i){
      const float4* Tr = (const float4*)&Tl[i * 68];
      float s0 = 0.f, s1 = 0.f, s2 = 0.f, s3 = 0.f;
      #pragma unroll
      for (int cc = 0; cc < 16; ++cc){
        float4 tv = Tr[cc];
        s0 = fmaf(tv.x, wv[4*cc],     s0);
        s1 = fmaf(tv.y, wv[4*cc + 1], s1);
        s2 = fmaf(tv.z, wv[4*cc + 2], s2);
        s3 = fmaf(tv.w, wv[4*cc + 3], s3);
      }
      St[lane * 68 + i] = ((s0 + s1) + (s2 + s3)) + Tl[i * 68 + 64] * wv[64];
    }
  }
  __syncthreads();

  // ---- D: M~[d][c] -> ws bf16 image [64][72]; bias col fp32 ----
  {
    const float inv = 1.0f / 65536.0f;   // 1/(sqrt(64)*8192)
    float wq[64];
    #pragma unroll
    for (int i = 0; i < 64; ++i) wq[i] = Wq[i * 64 + lane];   // column c = lane
    u16* Mb = Mws + (size_t)b * 64 * 72;
    for (int d = w * 8; d < w * 8 + 8; ++d){
      const float4* Sr = (const float4*)&St[d * 68];
      float s0 = 0.f, s1 = 0.f, s2 = 0.f, s3 = 0.f;
      #pragma unroll
      for (int ii = 0; ii < 16; ++ii){
        float4 sv = Sr[ii];
        s0 = fmaf(sv.x, wq[4*ii],     s0);
        s1 = fmaf(sv.y, wq[4*ii + 1], s1);
        s2 = fmaf(sv.z, wq[4*ii + 2], s2);
        s3 = fmaf(sv.w, wq[4*ii + 3], s3);
      }
      float val = fmaf(inv, (s0 + s1) + (s2 + s3), Ww[d * 64 + lane]);
      Mb[d * 72 + lane] = (u16)f2b_u(val);
    }
    if (w == 0){   // affine-const column, lane = d
      float s = 0.f;
      for (int i = 0; i < 64; ++i) s = fmaf(St[lane * 68 + i], bq[i], s);
      biasws[b * 64 + lane] = fmaf(inv, s, bw[lane]);
    }
  }
}

// ---------------------------------------------------------------------------
// K3: out = gelu(x~ M~^T) via MFMA. grid = 512 blocks (128/batch, 64 rows),
// 256 threads (4 waves: wi = row-half, wj = d-half).
// ---------------------------------------------------------------------------
__global__ __launch_bounds__(256) void k_out(const float* __restrict__ x,
                                             const u32* __restrict__ Mws,
                                             const float* __restrict__ biasws,
                                             float* __restrict__ out)
{
  int bid = blockIdx.x;
  int b = bid >> 7, blk = bid & 127;
  int t = threadIdx.x, w = t >> 6, lane = t & 63;
  int rowbase = blk * 64;

  __shared__ __align__(16) u16 Mb16[64][72];
  __shared__ __align__(16) u16 xR[64][72];
  __shared__ float Mbias[64];

  // copy M image (2304 u32) + bias
  {
    const u32* Msrc = Mws + (size_t)b * 2304;
    u32* Mdst = (u32*)&Mb16[0][0];
    #pragma unroll
    for (int i = 0; i < 9; ++i) Mdst[t + 256 * i] = Msrc[t + 256 * i];
    if (t < 64) Mbias[t] = biasws[b * 64 + t];
  }

  // stage 64 x rows, bf16 row-major
  {
    int r = t >> 2, cg = t & 3;
    const float4* src = (const float4*)(x + ((size_t)b * BN + rowbase + r) * 64 + cg * 16);
    float4 v0 = src[0], v1 = src[1], v2 = src[2], v3 = src[3];
    float vv[16] = { v0.x, v0.y, v0.z, v0.w,  v1.x, v1.y, v1.z, v1.w,
                     v2.x, v2.y, v2.z, v2.w,  v3.x, v3.y, v3.z, v3.w };
    #pragma unroll
    for (int j = 0; j < 8; ++j){
      u32 pk = f2b_u(vv[2*j]) | (f2b_u(vv[2*j+1]) << 16);
      *(u32*)&xR[r][cg * 16 + 2*j] = pk;
    }
  }
  __syncthreads();

  int wi = w >> 1, wj = w & 1;
  f32x16 oacc;
  #pragma unroll
  for (int i = 0; i < 16; ++i) oacc[i] = 0.f;
  #pragma unroll
  for (int ks = 0; ks < 4; ++ks){
    int c0 = ks * 16 + (lane >> 5) * 8;
    short8 af = *(const short8*)&xR  [wi * 32 + (lane & 31)][c0];
    short8 bf = *(const short8*)&Mb16[wj * 32 + (lane & 31)][c0];
    oacc = __builtin_amdgcn_mfma_f32_32x32x16_bf16(af, bf, oacc, 0, 0, 0);
  }

  float bias_v = Mbias[wj * 32 + (lane & 31)];
  int d = wj * 32 + (lane & 31);
  #pragma unroll
  for (int q = 0; q < 16; ++q){
    int n = rowbase + wi * 32 + (q & 3) + 8 * (q >> 2) + 4 * (lane >> 5);
    out[((size_t)b * BN + n) * 64 + d] = gelu_exact(oacc[q] + bias_v);
  }
}

// ---------------------------------------------------------------------------
extern "C" void kernel_launch(void* const* d_in, const int* in_sizes, int n_in,
                              void* d_out, int out_size, void* d_ws, size_t ws_size,
                              hipStream_t stream) {
  const float* x  = (const float*)d_in[0];
  const float* Wq = (const float*)d_in[1];
  const float* bq = (const float*)d_in[2];
  const float* Wk = (const float*)d_in[3];
  const float* bk = (const float*)d_in[4];
  const float* Wv = (const float*)d_in[5];
  const float* bv = (const float*)d_in[6];
  const float* Ww = (const float*)d_in[7];
  const float* bw = (const float*)d_in[8];
  float* out = (float*)d_out;

  float* ws     = (float*)d_ws;
  float* part   = ws;                           // floats [0, 532480)
  u16*   Mws    = (u16*)(ws + 532480);          // 4*64*72 u16 = 36864 B = 9216 floats
  float* biasws = ws + 532480 + 9216;           // floats [541696, 541952)

  k_gram   <<<dim3(4 * NPB), 256, 0, stream>>>(x, part);
  k_combine<<<dim3(4),       512, 0, stream>>>(part, Wq, bq, Wk, bk,
                                               Wv, bv, Ww, bw, Mws, biasws);
  k_out    <<<dim3(512),     256, 0, stream>>>(x, (const u32*)Mws, biasws, out);
}

// Round 13
// 38.899 us; speedup vs baseline: 9.7560x; 1.0701x over previous
//
#include <hip/hip_runtime.h>
#include <stdint.h>

typedef unsigned int u32;
typedef unsigned short u16;
typedef short short8 __attribute__((ext_vector_type(8)));
typedef float f32x16 __attribute__((ext_vector_type(16)));

#define BN 8192
#define NPB 32            // partial tiles per batch (256 rows each)
#define NT 4              // 64-row subtiles per gram block

__device__ __forceinline__ u32 f2b_u(float f){
  u32 x = __float_as_uint(f);
  return (x + 0x7fffu + ((x >> 16) & 1u)) >> 16;   // RNE f32->bf16
}
__device__ __forceinline__ float gelu_exact(float v){
  return 0.5f * v * (1.0f + erff(v * 0.70710678118654752440f));
}
__device__ __forceinline__ void add4(float4& a, const float4 b){
  a.x += b.x; a.y += b.y; a.z += b.z; a.w += b.w;
}

// ---------------------------------------------------------------------------
// K1: per-block partial Gram via MFMA. 256 rows per block (4 subtiles of 64).
// grid = 4*NPB = 128 blocks, 256 threads. (proven r10/r12)
// partial layout per block: 4096 floats G[i][j] + 64 floats m[j].
// ---------------------------------------------------------------------------
__global__ __launch_bounds__(256) void k_gram(const float* __restrict__ x,
                                              float* __restrict__ part){
  int bid = blockIdx.x;
  int b = bid >> 5, blk = bid & (NPB - 1);
  int t = threadIdx.x, w = t >> 6, lane = t & 63;
  const float* xb = x + (size_t)b * BN * 64 + (size_t)blk * 256 * 64;

  __shared__ __align__(16) u16 xT[64][72];     // [col][row] bf16, pad 72
  __shared__ float mred[256][16];

  int wi = w >> 1, wj = w & 1;
  int r = t >> 2, cg = t & 3;

  f32x16 acc;
  #pragma unroll
  for (int i = 0; i < 16; ++i) acc[i] = 0.f;
  float macc[16];
  #pragma unroll
  for (int j = 0; j < 16; ++j) macc[j] = 0.f;

  for (int tile = 0; tile < NT; ++tile){
    const float4* src = (const float4*)(xb + ((size_t)(tile * 64 + r)) * 64 + cg * 16);
    float4 v0 = src[0], v1 = src[1], v2 = src[2], v3 = src[3];
    float vv[16] = { v0.x, v0.y, v0.z, v0.w,  v1.x, v1.y, v1.z, v1.w,
                     v2.x, v2.y, v2.z, v2.w,  v3.x, v3.y, v3.z, v3.w };
    #pragma unroll
    for (int j = 0; j < 16; ++j){
      macc[j] += vv[j];
      xT[cg * 16 + j][r] = (u16)f2b_u(vv[j]);
    }
    __syncthreads();

    #pragma unroll
    for (int ks = 0; ks < 4; ++ks){
      int n0 = ks * 16 + (lane >> 5) * 8;
      short8 af = *(const short8*)&xT[wi * 32 + (lane & 31)][n0];
      short8 bf = *(const short8*)&xT[wj * 32 + (lane & 31)][n0];
      acc = __builtin_amdgcn_mfma_f32_32x32x16_bf16(af, bf, acc, 0, 0, 0);
    }
    __syncthreads();
  }

  // C/D map: col = lane&31, row = (reg&3) + 8*(reg>>2) + 4*(lane>>5)
  float* dst = part + (size_t)bid * 4160;
  #pragma unroll
  for (int q = 0; q < 16; ++q){
    int grow = wi * 32 + (q & 3) + 8 * (q >> 2) + 4 * (lane >> 5);
    dst[grow * 64 + wj * 32 + (lane & 31)] = acc[q];
  }

  #pragma unroll
  for (int j = 0; j < 16; ++j) mred[t][j] = macc[j];
  __syncthreads();
  if (t < 64){
    int cgc = t >> 4, j = t & 15;
    float s0 = 0.f, s1 = 0.f, s2 = 0.f, s3 = 0.f;
    for (int ss = 0; ss < 64; ss += 4){
      s0 += mred[cgc + 4 * ss][j];
      s1 += mred[cgc + 4 * (ss + 1)][j];
      s2 += mred[cgc + 4 * (ss + 2)][j];
      s3 += mred[cgc + 4 * (ss + 3)][j];
    }
    dst[4096 + t] = (s0 + s1) + (s2 + s3);
  }
}

// ---------------------------------------------------------------------------
// K2: WIDE reduction of 32 partials -> Gred. grid = 4*65 = 260 blocks, 64 thr.
// Block (b, chunk) covers float4-elems [chunk*16, chunk*16+16) of batch b.
// Lane group pg = t>>4 sums partials [pg*8, pg*8+8); LDS fold of 4 groups.
// ---------------------------------------------------------------------------
__global__ __launch_bounds__(64) void k_reduceW(const float4* __restrict__ part4,
                                                float4* __restrict__ Gred4){
  int blk = blockIdx.x;
  int b = blk / 65, chunk = blk - b * 65;
  int t = threadIdx.x;
  int e4 = chunk * 16 + (t & 15);
  int pg = t >> 4;

  __shared__ float4 red[4][16];

  const float4* base = part4 + (size_t)b * NPB * 1040 + e4;
  float4 s = make_float4(0.f, 0.f, 0.f, 0.f);
  #pragma unroll
  for (int p = 0; p < 8; ++p)
    add4(s, base[(size_t)(pg * 8 + p) * 1040]);
  red[pg][t & 15] = s;
  __syncthreads();

  if (t < 16){
    float4 a = red[0][t], c = red[1][t];
    add4(a, red[2][t]);
    add4(c, red[3][t]);
    add4(a, c);
    Gred4[(size_t)b * 1040 + chunk * 16 + t] = a;
  }
}

// ---------------------------------------------------------------------------
// K3: per-batch combine, small input. grid = 4 blocks, 512 threads.
//  A: load Gred (16.6 KB coalesced) -> Gt (LDS, G + m borders)
//  B: T = W~k G~   C: St = S^T   D: M~ -> ws as bf16 [64][72] image + f32 bias
// ---------------------------------------------------------------------------
__global__ __launch_bounds__(512) void k_combineS(
    const float4* __restrict__ Gred4,
    const float* __restrict__ Wq, const float* __restrict__ bq,
    const float* __restrict__ Wk, const float* __restrict__ bk,
    const float* __restrict__ Wv, const float* __restrict__ bv,
    const float* __restrict__ Ww, const float* __restrict__ bw,
    u16* __restrict__ Mws, float* __restrict__ biasws)
{
  int b = blockIdx.x;
  int t = threadIdx.x, w = t >> 6, lane = t & 63;

  __shared__ __align__(16) float Gt[65 * 68];
  __shared__ __align__(16) float Tl[64 * 68];
  __shared__ __align__(16) float St[64 * 68];

  // ---- A: load Gred into Gt ----
  {
    const float4* Gb4 = Gred4 + (size_t)b * 1040;
    for (int g = t; g < 1040; g += 512){
      float4 v = Gb4[g];
      if (g < 1024){
        *(float4*)&Gt[(g >> 4) * 68 + (g & 15) * 4] = v;
      } else {
        int j0 = (g - 1024) * 4;
        float mv[4] = { v.x, v.y, v.z, v.w };
        #pragma unroll
        for (int k = 0; k < 4; ++k){
          Gt[64 * 68 + j0 + k] = mv[k];
          Gt[(j0 + k) * 68 + 64] = mv[k];
        }
      }
    }
    if (t == 0) Gt[64 * 68 + 64] = (float)BN;
  }
  __syncthreads();

  // ---- B: T[i][c] = sum_a W~k[i][a] G~[a][c], c = lane; 8 rows/wave ----
  {
    float gcol[65];
    #pragma unroll
    for (int a = 0; a < 65; ++a) gcol[a] = Gt[a * 68 + lane];
    for (int i = w * 8; i < w * 8 + 8; ++i){
      float s0 = 0.f, s1 = 0.f, s2 = 0.f, s3 = 0.f;
      #pragma unroll
      for (int a = 0; a < 64; a += 4){
        s0 = fmaf(Wk[i * 64 + a],     gcol[a],     s0);
        s1 = fmaf(Wk[i * 64 + a + 1], gcol[a + 1], s1);
        s2 = fmaf(Wk[i * 64 + a + 2], gcol[a + 2], s2);
        s3 = fmaf(Wk[i * 64 + a + 3], gcol[a + 3], s3);
      }
      Tl[i * 68 + lane] = ((s0 + s1) + (s2 + s3)) + bk[i] * gcol[64];
    }
  }
  if (w == 0){   // column 64 of T, lane = i
    float s = 0.f;
    for (int a = 0; a < 64; ++a)
      s = fmaf(Wk[lane * 64 + a], Gt[a * 68 + 64], s);
    s = fmaf(bk[lane], (float)BN, s);
    Tl[lane * 68 + 64] = s;
  }
  __syncthreads();

  // ---- C: St[j][i] = S[i][j] = sum_c T[i][c] W~v[j][c], j = lane ----
  {
    float wv[65];
    const float4* Wv4 = (const float4*)(Wv + (size_t)lane * 64);
    #pragma unroll
    for (int c4 = 0; c4 < 16; ++c4){
      float4 vv = Wv4[c4];
      wv[4*c4] = vv.x; wv[4*c4+1] = vv.y; wv[4*c4+2] = vv.z; wv[4*c4+3] = vv.w;
    }
    wv[64] = bv[lane];
    for (int i = w * 8; i < w * 8 + 8; ++i){
      const float4* Tr = (const float4*)&Tl[i * 68];
      float s0 = 0.f, s1 = 0.f, s2 = 0.f, s3 = 0.f;
      #pragma unroll
      for (int cc = 0; cc < 16; ++cc){
        float4 tv = Tr[cc];
        s0 = fmaf(tv.x, wv[4*cc],     s0);
        s1 = fmaf(tv.y, wv[4*cc + 1], s1);
        s2 = fmaf(tv.z, wv[4*cc + 2], s2);
        s3 = fmaf(tv.w, wv[4*cc + 3], s3);
      }
      St[lane * 68 + i] = ((s0 + s1) + (s2 + s3)) + Tl[i * 68 + 64] * wv[64];
    }
  }
  __syncthreads();

  // ---- D: M~[d][c] -> ws bf16 image [64][72]; bias col fp32 ----
  {
    const float inv = 1.0f / 65536.0f;   // 1/(sqrt(64)*8192)
    float wq[64];
    #pragma unroll
    for (int i = 0; i < 64; ++i) wq[i] = Wq[i * 64 + lane];   // column c = lane
    u16* Mb = Mws + (size_t)b * 64 * 72;
    for (int d = w * 8; d < w * 8 + 8; ++d){
      const float4* Sr = (const float4*)&St[d * 68];
      float s0 = 0.f, s1 = 0.f, s2 = 0.f, s3 = 0.f;
      #pragma unroll
      for (int ii = 0; ii < 16; ++ii){
        float4 sv = Sr[ii];
        s0 = fmaf(sv.x, wq[4*ii],     s0);
        s1 = fmaf(sv.y, wq[4*ii + 1], s1);
        s2 = fmaf(sv.z, wq[4*ii + 2], s2);
        s3 = fmaf(sv.w, wq[4*ii + 3], s3);
      }
      float val = fmaf(inv, (s0 + s1) + (s2 + s3), Ww[d * 64 + lane]);
      Mb[d * 72 + lane] = (u16)f2b_u(val);
    }
    if (w == 0){   // affine-const column, lane = d
      float s = 0.f;
      for (int i = 0; i < 64; ++i) s = fmaf(St[lane * 68 + i], bq[i], s);
      biasws[b * 64 + lane] = fmaf(inv, s, bw[lane]);
    }
  }
}

// ---------------------------------------------------------------------------
// K4: out = gelu(x~ M~^T) via MFMA. grid = 512 blocks (128/batch, 64 rows),
// 256 threads (4 waves: wi = row-half, wj = d-half). (proven r12)
// ---------------------------------------------------------------------------
__global__ __launch_bounds__(256) void k_out(const float* __restrict__ x,
                                             const u32* __restrict__ Mws,
                                             const float* __restrict__ biasws,
                                             float* __restrict__ out)
{
  int bid = blockIdx.x;
  int b = bid >> 7, blk = bid & 127;
  int t = threadIdx.x, w = t >> 6, lane = t & 63;
  int rowbase = blk * 64;

  __shared__ __align__(16) u16 Mb16[64][72];
  __shared__ __align__(16) u16 xR[64][72];
  __shared__ float Mbias[64];

  // copy M image (2304 u32) + bias
  {
    const u32* Msrc = Mws + (size_t)b * 2304;
    u32* Mdst = (u32*)&Mb16[0][0];
    #pragma unroll
    for (int i = 0; i < 9; ++i) Mdst[t + 256 * i] = Msrc[t + 256 * i];
    if (t < 64) Mbias[t] = biasws[b * 64 + t];
  }

  // stage 64 x rows, bf16 row-major
  {
    int r = t >> 2, cg = t & 3;
    const float4* src = (const float4*)(x + ((size_t)b * BN + rowbase + r) * 64 + cg * 16);
    float4 v0 = src[0], v1 = src[1], v2 = src[2], v3 = src[3];
    float vv[16] = { v0.x, v0.y, v0.z, v0.w,  v1.x, v1.y, v1.z, v1.w,
                     v2.x, v2.y, v2.z, v2.w,  v3.x, v3.y, v3.z, v3.w };
    #pragma unroll
    for (int j = 0; j < 8; ++j){
      u32 pk = f2b_u(vv[2*j]) | (f2b_u(vv[2*j+1]) << 16);
      *(u32*)&xR[r][cg * 16 + 2*j] = pk;
    }
  }
  __syncthreads();

  int wi = w >> 1, wj = w & 1;
  f32x16 oacc;
  #pragma unroll
  for (int i = 0; i < 16; ++i) oacc[i] = 0.f;
  #pragma unroll
  for (int ks = 0; ks < 4; ++ks){
    int c0 = ks * 16 + (lane >> 5) * 8;
    short8 af = *(const short8*)&xR  [wi * 32 + (lane & 31)][c0];
    short8 bf = *(const short8*)&Mb16[wj * 32 + (lane & 31)][c0];
    oacc = __builtin_amdgcn_mfma_f32_32x32x16_bf16(af, bf, oacc, 0, 0, 0);
  }

  float bias_v = Mbias[wj * 32 + (lane & 31)];
  int d = wj * 32 + (lane & 31);
  #pragma unroll
  for (int q = 0; q < 16; ++q){
    int n = rowbase + wi * 32 + (q & 3) + 8 * (q >> 2) + 4 * (lane >> 5);
    out[((size_t)b * BN + n) * 64 + d] = gelu_exact(oacc[q] + bias_v);
  }
}

// ---------------------------------------------------------------------------
extern "C" void kernel_launch(void* const* d_in, const int* in_sizes, int n_in,
                              void* d_out, int out_size, void* d_ws, size_t ws_size,
                              hipStream_t stream) {
  const float* x  = (const float*)d_in[0];
  const float* Wq = (const float*)d_in[1];
  const float* bq = (const float*)d_in[2];
  const float* Wk = (const float*)d_in[3];
  const float* bk = (const float*)d_in[4];
  const float* Wv = (const float*)d_in[5];
  const float* bv = (const float*)d_in[6];
  const float* Ww = (const float*)d_in[7];
  const float* bw = (const float*)d_in[8];
  float* out = (float*)d_out;

  float* ws     = (float*)d_ws;
  float* part   = ws;                     // floats [0, 532480)
  float* Gred   = ws + 532480;            // 4*4160 = 16640 floats
  u16*   Mws    = (u16*)(ws + 549120);    // 9216 floats worth (36864 B)
  float* biasws = ws + 549120 + 9216;     // 256 floats

  k_gram    <<<dim3(4 * NPB), 256, 0, stream>>>(x, part);
  k_reduceW <<<dim3(260),      64, 0, stream>>>((const float4*)part, (float4*)Gred);
  k_combineS<<<dim3(4),       512, 0, stream>>>((const float4*)Gred, Wq, bq, Wk, bk,
                                                Wv, bv, Ww, bw, Mws, biasws);
  k_out     <<<dim3(512),     256, 0, stream>>>(x, (const u32*)Mws, biasws, out);
}